// Round 2
// baseline (66.692 us; speedup 1.0000x reference)
//
#include <hip/hip_runtime.h>
#include <hip/hip_bf16.h>

#define T 32
#define WAYS 64
#define SHOTS 8
#define CDIM 1024
#define WQ 1024

typedef float f32x4 __attribute__((ext_vector_type(4)));
typedef __bf16 bf16x8 __attribute__((ext_vector_type(8)));

// Kernel 1: proto = mean over shots (stored bf16), p_sq = ||proto||^2 (fp32)
__global__ __launch_bounds__(256) void proto_kernel(const float* __restrict__ support,
                                                    __bf16* __restrict__ proto,
                                                    float* __restrict__ p_sq) {
    const int bid = blockIdx.x;          // t*64 + way
    const int tid = threadIdx.x;         // 256 threads, 1 float4 of c each
    const float* sp = support + (size_t)bid * (SHOTS * CDIM);
    float4 a = make_float4(0.f, 0.f, 0.f, 0.f);
#pragma unroll
    for (int s = 0; s < SHOTS; ++s) {
        const float4 v = *reinterpret_cast<const float4*>(sp + s * CDIM + tid * 4);
        a.x += v.x; a.y += v.y; a.z += v.z; a.w += v.w;
    }
    a.x *= 0.125f; a.y *= 0.125f; a.z *= 0.125f; a.w *= 0.125f;
    float ps = a.x * a.x + a.y * a.y + a.z * a.z + a.w * a.w;

    union { __bf16 h[4]; uint2 u; } pk;
    pk.h[0] = (__bf16)a.x; pk.h[1] = (__bf16)a.y; pk.h[2] = (__bf16)a.z; pk.h[3] = (__bf16)a.w;
    *reinterpret_cast<uint2*>(proto + (size_t)bid * CDIM + tid * 4) = pk.u;

    // block-reduce ps
#pragma unroll
    for (int m = 32; m >= 1; m >>= 1) ps += __shfl_down(ps, m, 64);
    __shared__ float red[4];
    const int wv = tid >> 6, ln = tid & 63;
    if (ln == 0) red[wv] = ps;
    __syncthreads();
    if (tid == 0) p_sq[bid] = red[0] + red[1] + red[2] + red[3];
}

// Kernel 2: barrier-free, LDS-free. One wave owns 16 query rows x all 64 ways.
// A fragments straight from global f32 (convert to bf16 in-reg, fuse qsq),
// B fragments straight from L2-resident bf16 proto. 4-deep register prefetch.
__global__ __launch_bounds__(256) void dist_kernel(const float* __restrict__ query,
                                                   const __bf16* __restrict__ proto,
                                                   const float* __restrict__ p_sq,
                                                   float* __restrict__ out) {
    const int bx   = blockIdx.x;
    const int t    = bx >> 4;
    const int wv   = threadIdx.x >> 6;
    const int lane = threadIdx.x & 63;
    const int rg   = (bx & 15) * 4 + wv;     // row-group 0..63 (16 rows each)
    const int r16  = lane & 15;
    const int kg   = lane >> 4;              // k-group 0..3

    // lane-fixed base pointers
    const float*  qp = query + ((size_t)(t * WQ + rg * 16 + r16)) * CDIM + kg * 8;
    const __bf16* pb = proto + ((size_t)(t * WAYS + r16)) * CDIM + kg * 8;

    f32x4 acc[4];
#pragma unroll
    for (int n = 0; n < 4; ++n) acc[n] = (f32x4){0.f, 0.f, 0.f, 0.f};
    float qsq = 0.f;

    struct Stage { f32x4 a0, a1; uint4 b0, b1, b2, b3; };

    auto LOAD = [&](int ks) -> Stage {
        Stage s;
        const float* ap = qp + ks * 32;
        s.a0 = *reinterpret_cast<const f32x4*>(ap);
        s.a1 = *reinterpret_cast<const f32x4*>(ap + 4);
        const __bf16* bp = pb + ks * 32;
        s.b0 = *reinterpret_cast<const uint4*>(bp);
        s.b1 = *reinterpret_cast<const uint4*>(bp + 16 * CDIM);
        s.b2 = *reinterpret_cast<const uint4*>(bp + 32 * CDIM);
        s.b3 = *reinterpret_cast<const uint4*>(bp + 48 * CDIM);
        return s;
    };

    auto COMPUTE = [&](const Stage& s) {
        qsq += s.a0.x * s.a0.x + s.a0.y * s.a0.y + s.a0.z * s.a0.z + s.a0.w * s.a0.w +
               s.a1.x * s.a1.x + s.a1.y * s.a1.y + s.a1.z * s.a1.z + s.a1.w * s.a1.w;
        union { bf16x8 h; struct { __bf16 e0,e1,e2,e3,e4,e5,e6,e7; } e; } af;
        af.e.e0 = (__bf16)s.a0.x; af.e.e1 = (__bf16)s.a0.y;
        af.e.e2 = (__bf16)s.a0.z; af.e.e3 = (__bf16)s.a0.w;
        af.e.e4 = (__bf16)s.a1.x; af.e.e5 = (__bf16)s.a1.y;
        af.e.e6 = (__bf16)s.a1.z; af.e.e7 = (__bf16)s.a1.w;
        union { uint4 u; bf16x8 h; } b0{s.b0}, b1{s.b1}, b2{s.b2}, b3{s.b3};
        acc[0] = __builtin_amdgcn_mfma_f32_16x16x32_bf16(af.h, b0.h, acc[0], 0, 0, 0);
        acc[1] = __builtin_amdgcn_mfma_f32_16x16x32_bf16(af.h, b1.h, acc[1], 0, 0, 0);
        acc[2] = __builtin_amdgcn_mfma_f32_16x16x32_bf16(af.h, b2.h, acc[2], 0, 0, 0);
        acc[3] = __builtin_amdgcn_mfma_f32_16x16x32_bf16(af.h, b3.h, acc[3], 0, 0, 0);
    };

    Stage S0 = LOAD(0), S1 = LOAD(1), S2 = LOAD(2), S3 = LOAD(3);
#pragma unroll
    for (int k = 0; k < 32; k += 4) {
        COMPUTE(S0); if (k + 4 < 32) S0 = LOAD(k + 4);
        COMPUTE(S1); if (k + 5 < 32) S1 = LOAD(k + 5);
        COMPUTE(S2); if (k + 6 < 32) S2 = LOAD(k + 6);
        COMPUTE(S3); if (k + 7 < 32) S3 = LOAD(k + 7);
    }

    // qsq: sum the 4 k-group partials -> every lane holds qsq for row (lane&15)
    qsq += __shfl_xor(qsq, 16, 64);
    qsq += __shfl_xor(qsq, 32, 64);

    float psqv[4];
#pragma unroll
    for (int n = 0; n < 4; ++n) psqv[n] = p_sq[t * WAYS + n * 16 + r16];

    float* ob = out + ((size_t)(t * WQ + rg * 16)) * WAYS;
#pragma unroll
    for (int r = 0; r < 4; ++r) {
        const int row = kg * 4 + r;               // local row 0..15
        const float qv = __shfl(qsq, row, 64);    // lane `row` holds that row's qsq
#pragma unroll
        for (int n = 0; n < 4; ++n) {
            ob[(size_t)row * WAYS + n * 16 + r16] = 2.f * acc[n][r] - qv - psqv[n];
        }
    }
}

extern "C" void kernel_launch(void* const* d_in, const int* in_sizes, int n_in,
                              void* d_out, int out_size, void* d_ws, size_t ws_size,
                              hipStream_t stream) {
    const float* query   = (const float*)d_in[0];
    const float* support = (const float*)d_in[1];
    float* out = (float*)d_out;

    __bf16* proto = (__bf16*)d_ws;                                   // 4 MB
    float*  p_sq  = (float*)((char*)d_ws + (size_t)T * WAYS * CDIM * sizeof(__bf16));

    hipLaunchKernelGGL(proto_kernel, dim3(T * WAYS), dim3(256), 0, stream,
                       support, proto, p_sq);
    hipLaunchKernelGGL(dist_kernel, dim3(T * 16), dim3(256), 0, stream,
                       query, proto, p_sq, out);
}

// Round 3
// 41.659 us; speedup vs baseline: 1.6009x; 1.6009x over previous
//
#include <hip/hip_runtime.h>
#include <hip/hip_bf16.h>

#define T 32
#define WAYS 64
#define SHOTS 8
#define CDIM 1024
#define WQ 1024
#define NK 16   // K-steps of 64

typedef float f32x4 __attribute__((ext_vector_type(4)));
typedef __bf16 bf16x8 __attribute__((ext_vector_type(8)));

// Kernel 1: proto = mean over shots (stored bf16), p_sq = ||proto||^2 (fp32)
__global__ __launch_bounds__(256) void proto_kernel(const float* __restrict__ support,
                                                    __bf16* __restrict__ proto,
                                                    float* __restrict__ p_sq) {
    const int bid = blockIdx.x;          // t*64 + way
    const int tid = threadIdx.x;
    const float* sp = support + (size_t)bid * (SHOTS * CDIM);
    float4 a = make_float4(0.f, 0.f, 0.f, 0.f);
#pragma unroll
    for (int s = 0; s < SHOTS; ++s) {
        const float4 v = *reinterpret_cast<const float4*>(sp + s * CDIM + tid * 4);
        a.x += v.x; a.y += v.y; a.z += v.z; a.w += v.w;
    }
    a.x *= 0.125f; a.y *= 0.125f; a.z *= 0.125f; a.w *= 0.125f;
    float ps = a.x * a.x + a.y * a.y + a.z * a.z + a.w * a.w;

    union { __bf16 h[4]; uint2 u; } pk;
    pk.h[0] = (__bf16)a.x; pk.h[1] = (__bf16)a.y; pk.h[2] = (__bf16)a.z; pk.h[3] = (__bf16)a.w;
    *reinterpret_cast<uint2*>(proto + (size_t)bid * CDIM + tid * 4) = pk.u;

#pragma unroll
    for (int m = 32; m >= 1; m >>= 1) ps += __shfl_down(ps, m, 64);
    __shared__ float red[4];
    const int wv = tid >> 6, ln = tid & 63;
    if (ln == 0) red[wv] = ps;
    __syncthreads();
    if (tid == 0) p_sq[bid] = red[0] + red[1] + red[2] + red[3];
}

// Kernel 2: 512 threads / 8 waves per block, block = 64 rows x 64 ways x K=1024.
// Wave = 16 rows x 32 ways. Double-buffered LDS, ONE raw barrier per K-step
// (lgkmcnt(0) only -- vmcnt never drained, loads stay in flight across barriers),
// depth-2 register prefetch, qsq fused into A staging, XOR-swizzled LDS.
__global__ __launch_bounds__(512, 4) void dist_kernel(const float* __restrict__ query,
                                                      const __bf16* __restrict__ proto,
                                                      const float* __restrict__ p_sq,
                                                      float* __restrict__ out) {
    const int bx  = blockIdx.x;
    const int t   = bx >> 4;
    const int mt  = bx & 15;
    const int tid = threadIdx.x;
    const int lane = tid & 63;
    const int wid  = tid >> 6;
    const int wr   = wid >> 1;      // 0..3 : row group of 16
    const int wn   = wid & 1;       // 0..1 : way half of 32
    const int fr   = lane & 15;
    const int kg   = lane >> 4;

    __shared__ __bf16 As[2][64 * 64];
    __shared__ __bf16 Bs[2][64 * 64];
    __shared__ float qsq_s[64];

    // staging: thread -> (row 0..63, 8 k-elements)
    const int srow = tid >> 3;
    const int sk8  = tid & 7;

    const float*  qbase = query + ((size_t)(t * WQ + mt * 64 + srow)) * CDIM;
    const __bf16* pbase = proto + ((size_t)(t * WAYS + srow)) * CDIM;

    struct Stage { f32x4 a0, a1; uint4 b; };

    auto LOAD = [&](int ks) -> Stage {
        Stage s;
        // A row: 64 f32 per K-step; halves so each instr is 128B-contiguous/row
        s.a0 = *reinterpret_cast<const f32x4*>(qbase + ks * 64 + sk8 * 4);
        s.a1 = *reinterpret_cast<const f32x4*>(qbase + ks * 64 + 32 + sk8 * 4);
        s.b  = *reinterpret_cast<const uint4*>(pbase + ks * 64 + sk8 * 8);
        return s;
    };

    float qsq = 0.f;

    auto WRITE = [&](int buf, const Stage& s) {
        qsq += s.a0.x * s.a0.x + s.a0.y * s.a0.y + s.a0.z * s.a0.z + s.a0.w * s.a0.w +
               s.a1.x * s.a1.x + s.a1.y * s.a1.y + s.a1.z * s.a1.z + s.a1.w * s.a1.w;
        union { __bf16 h[4]; uint2 u; } p0, p1;
        p0.h[0] = (__bf16)s.a0.x; p0.h[1] = (__bf16)s.a0.y;
        p0.h[2] = (__bf16)s.a0.z; p0.h[3] = (__bf16)s.a0.w;
        p1.h[0] = (__bf16)s.a1.x; p1.h[1] = (__bf16)s.a1.y;
        p1.h[2] = (__bf16)s.a1.z; p1.h[3] = (__bf16)s.a1.w;
        char* ab = reinterpret_cast<char*>(As[buf]);
        const int swz = (srow & 7) << 4;
        *reinterpret_cast<uint2*>(ab + ((srow * 128 + sk8 * 8) ^ swz))      = p0.u;
        *reinterpret_cast<uint2*>(ab + ((srow * 128 + 64 + sk8 * 8) ^ swz)) = p1.u;
        char* bb = reinterpret_cast<char*>(Bs[buf]);
        *reinterpret_cast<uint4*>(bb + ((srow * 128 + sk8 * 16) ^ swz))     = s.b;
    };

    f32x4 acc[2];
    acc[0] = (f32x4){0.f, 0.f, 0.f, 0.f};
    acc[1] = (f32x4){0.f, 0.f, 0.f, 0.f};

    auto COMPUTE = [&](int buf) {
        const char* ab = reinterpret_cast<const char*>(As[buf]);
        const char* bb = reinterpret_cast<const char*>(Bs[buf]);
#pragma unroll
        for (int ksub = 0; ksub < 2; ++ksub) {
            const int arow = wr * 16 + fr;
            const bf16x8 af = *reinterpret_cast<const bf16x8*>(
                ab + ((arow * 128 + ksub * 64 + kg * 16) ^ ((arow & 7) << 4)));
#pragma unroll
            for (int nf = 0; nf < 2; ++nf) {
                const int way = wn * 32 + nf * 16 + fr;
                const bf16x8 bf = *reinterpret_cast<const bf16x8*>(
                    bb + ((way * 128 + ksub * 64 + kg * 16) ^ ((way & 7) << 4)));
                acc[nf] = __builtin_amdgcn_mfma_f32_16x16x32_bf16(af, bf, acc[nf], 0, 0, 0);
            }
        }
    };

    // prologue: stage tile 0, issue tiles 1 and 2
    Stage s0 = LOAD(0);
    Stage sA = LOAD(1);
    Stage sB = LOAD(2);
    WRITE(0, s0);
    asm volatile("s_waitcnt lgkmcnt(0)" ::: "memory");
    __builtin_amdgcn_s_barrier();

#pragma unroll
    for (int ks = 0; ks < NK; ++ks) {
        Stage nx;
        if (ks < NK - 3) nx = LOAD(ks + 3);          // issue early, consume 2 iters later
        COMPUTE(ks & 1);
        if (ks < NK - 1) WRITE((ks + 1) & 1, sA);    // other buffer: no read/write hazard
        sA = sB; sB = nx;                            // full unroll -> renamed, stays in regs
        asm volatile("s_waitcnt lgkmcnt(0)" ::: "memory");
        __builtin_amdgcn_s_barrier();                // vmcnt NOT drained
    }

    // qsq: reduce over the 8 staging threads of each row (same wave, lanes ^1^2^4)
    qsq += __shfl_xor(qsq, 1, 64);
    qsq += __shfl_xor(qsq, 2, 64);
    qsq += __shfl_xor(qsq, 4, 64);
    if (sk8 == 0) qsq_s[srow] = qsq;
    __syncthreads();

    float psqv[2];
#pragma unroll
    for (int nf = 0; nf < 2; ++nf)
        psqv[nf] = p_sq[t * WAYS + wn * 32 + nf * 16 + fr];

    float* ob = out + ((size_t)(t * WQ + mt * 64 + wr * 16)) * WAYS;
#pragma unroll
    for (int r = 0; r < 4; ++r) {
        const int row = kg * 4 + r;                  // local row 0..15 in this wave's group
        const float qv = qsq_s[wr * 16 + row];
#pragma unroll
        for (int nf = 0; nf < 2; ++nf) {
            ob[(size_t)row * WAYS + wn * 32 + nf * 16 + fr] =
                2.f * acc[nf][r] - qv - psqv[nf];
        }
    }
}

extern "C" void kernel_launch(void* const* d_in, const int* in_sizes, int n_in,
                              void* d_out, int out_size, void* d_ws, size_t ws_size,
                              hipStream_t stream) {
    const float* query   = (const float*)d_in[0];
    const float* support = (const float*)d_in[1];
    float* out = (float*)d_out;

    __bf16* proto = (__bf16*)d_ws;                                   // 4 MB
    float*  p_sq  = (float*)((char*)d_ws + (size_t)T * WAYS * CDIM * sizeof(__bf16));

    hipLaunchKernelGGL(proto_kernel, dim3(T * WAYS), dim3(256), 0, stream,
                       support, proto, p_sq);
    hipLaunchKernelGGL(dist_kernel, dim3(T * 16), dim3(512), 0, stream,
                       query, proto, p_sq, out);
}

// Round 5
// 38.873 us; speedup vs baseline: 1.7157x; 1.0717x over previous
//
#include <hip/hip_runtime.h>
#include <hip/hip_bf16.h>

#define T 32
#define WAYS 64
#define SHOTS 8
#define CDIM 1024
#define WQ 1024
#define BK 128
#define NK 8    // K-steps of 128

typedef float f32x4 __attribute__((ext_vector_type(4)));
typedef __bf16 bf16x8 __attribute__((ext_vector_type(8)));

// Kernel 1: proto = mean over shots (stored bf16), p_sq = ||proto||^2 (fp32)
__global__ __launch_bounds__(256) void proto_kernel(const float* __restrict__ support,
                                                    __bf16* __restrict__ proto,
                                                    float* __restrict__ p_sq) {
    const int bid = blockIdx.x;          // t*64 + way
    const int tid = threadIdx.x;
    const float* sp = support + (size_t)bid * (SHOTS * CDIM);
    float4 a = make_float4(0.f, 0.f, 0.f, 0.f);
#pragma unroll
    for (int s = 0; s < SHOTS; ++s) {
        const float4 v = *reinterpret_cast<const float4*>(sp + s * CDIM + tid * 4);
        a.x += v.x; a.y += v.y; a.z += v.z; a.w += v.w;
    }
    a.x *= 0.125f; a.y *= 0.125f; a.z *= 0.125f; a.w *= 0.125f;
    float ps = a.x * a.x + a.y * a.y + a.z * a.z + a.w * a.w;

    union { __bf16 h[4]; uint2 u; } pk;
    pk.h[0] = (__bf16)a.x; pk.h[1] = (__bf16)a.y; pk.h[2] = (__bf16)a.z; pk.h[3] = (__bf16)a.w;
    *reinterpret_cast<uint2*>(proto + (size_t)bid * CDIM + tid * 4) = pk.u;

#pragma unroll
    for (int m = 32; m >= 1; m >>= 1) ps += __shfl_down(ps, m, 64);
    __shared__ float red[4];
    const int wv = tid >> 6, ln = tid & 63;
    if (ln == 0) red[wv] = ps;
    __syncthreads();
    if (tid == 0) p_sq[bid] = red[0] + red[1] + red[2] + red[3];
}

// Kernel 2: 512 threads / 8 waves, block = 64 rows x 64 ways, BK=128.
// Wave = 16 rows x 32 ways. Double-buffered LDS, ONE raw barrier per K-step
// (lgkmcnt(0) only -- vmcnt never drained in-loop), depth-2 register prefetch,
// qsq fused into A staging, XOR-swizzled LDS, XCD-chunked block mapping.
__global__ __launch_bounds__(512, 4) void dist_kernel(const float* __restrict__ query,
                                                      const __bf16* __restrict__ proto,
                                                      const float* __restrict__ p_sq,
                                                      float* __restrict__ out) {
    const int bx = blockIdx.x;
    const int vb = (bx & 7) * 64 + (bx >> 3);   // XCD-chunked: episode t -> one XCD
    const int t   = vb >> 4;
    const int mt  = vb & 15;
    const int tid = threadIdx.x;
    const int lane = tid & 63;
    const int wid  = tid >> 6;
    const int wr   = wid >> 1;      // 0..3 : row group of 16
    const int wn   = wid & 1;       // 0..1 : way half of 32
    const int fr   = lane & 15;
    const int kg   = lane >> 4;

    __shared__ __bf16 As[2][64 * BK];
    __shared__ __bf16 Bs[2][64 * BK];
    __shared__ float qsq_s[64];

    // staging: thread -> (row 0..63, 16 f32 of A / 16 bf16 of B per K-step)
    const int srow = tid >> 3;
    const int sk8  = tid & 7;

    const float*  qbase = query + ((size_t)(t * WQ + mt * 64 + srow)) * CDIM + sk8 * 16;
    const __bf16* pbase = proto + ((size_t)(t * WAYS + srow)) * CDIM + sk8 * 16;

    struct Stage { f32x4 a[4]; uint4 b[2]; };

    auto LOAD = [&](int ks) -> Stage {
        Stage s;
        const float* ap = qbase + ks * BK;
#pragma unroll
        for (int p = 0; p < 4; ++p)
            s.a[p] = *reinterpret_cast<const f32x4*>(ap + p * 4);
        const __bf16* bp = pbase + ks * BK;
        s.b[0] = *reinterpret_cast<const uint4*>(bp);
        s.b[1] = *reinterpret_cast<const uint4*>(bp + 8);
        return s;
    };

    float qsq = 0.f;

    auto WRITE = [&](int buf, const Stage& s) {
#pragma unroll
        for (int p = 0; p < 4; ++p)
            qsq += s.a[p].x * s.a[p].x + s.a[p].y * s.a[p].y +
                   s.a[p].z * s.a[p].z + s.a[p].w * s.a[p].w;
        union { __bf16 h[8]; uint4 u; } p0, p1;
#pragma unroll
        for (int j = 0; j < 2; ++j) {
            const f32x4 v0 = s.a[j * 2], v1 = s.a[j * 2 + 1];
            __bf16* h = (j == 0) ? p0.h : p1.h;
            h[0] = (__bf16)v0.x; h[1] = (__bf16)v0.y; h[2] = (__bf16)v0.z; h[3] = (__bf16)v0.w;
            h[4] = (__bf16)v1.x; h[5] = (__bf16)v1.y; h[6] = (__bf16)v1.z; h[7] = (__bf16)v1.w;
        }
        const int swz = (srow & 7) << 4;
        char* ab = reinterpret_cast<char*>(As[buf]);
        *reinterpret_cast<uint4*>(ab + ((srow * 256 + sk8 * 32) ^ swz))      = p0.u;
        *reinterpret_cast<uint4*>(ab + ((srow * 256 + sk8 * 32 + 16) ^ swz)) = p1.u;
        char* bb = reinterpret_cast<char*>(Bs[buf]);
        *reinterpret_cast<uint4*>(bb + ((srow * 256 + sk8 * 32) ^ swz))      = s.b[0];
        *reinterpret_cast<uint4*>(bb + ((srow * 256 + sk8 * 32 + 16) ^ swz)) = s.b[1];
    };

    f32x4 acc[2];
    acc[0] = (f32x4){0.f, 0.f, 0.f, 0.f};
    acc[1] = (f32x4){0.f, 0.f, 0.f, 0.f};

    auto COMPUTE = [&](int buf) {
        const char* ab = reinterpret_cast<const char*>(As[buf]);
        const char* bb = reinterpret_cast<const char*>(Bs[buf]);
#pragma unroll
        for (int ksub = 0; ksub < 4; ++ksub) {
            const int arow = wr * 16 + fr;
            const bf16x8 af = *reinterpret_cast<const bf16x8*>(
                ab + ((arow * 256 + ksub * 64 + kg * 16) ^ ((arow & 7) << 4)));
#pragma unroll
            for (int nf = 0; nf < 2; ++nf) {
                const int way = wn * 32 + nf * 16 + fr;
                const bf16x8 bf = *reinterpret_cast<const bf16x8*>(
                    bb + ((way * 256 + ksub * 64 + kg * 16) ^ ((way & 7) << 4)));
                acc[nf] = __builtin_amdgcn_mfma_f32_16x16x32_bf16(af, bf, acc[nf], 0, 0, 0);
            }
        }
    };

    // hoist p_sq loads (held across the K-loop)
    float psqv[2];
#pragma unroll
    for (int nf = 0; nf < 2; ++nf)
        psqv[nf] = p_sq[t * WAYS + wn * 32 + nf * 16 + fr];

    // prologue: stage tile 0, issue tile 1
    Stage s0 = LOAD(0);
    Stage sA = LOAD(1);
    WRITE(0, s0);
    asm volatile("s_waitcnt lgkmcnt(0)" ::: "memory");
    __builtin_amdgcn_s_barrier();

#pragma unroll
    for (int ks = 0; ks < NK; ++ks) {
        Stage nx;
        if (ks < NK - 2) nx = LOAD(ks + 2);          // issue early, consume next iter
        COMPUTE(ks & 1);
        if (ks < NK - 1) WRITE((ks + 1) & 1, sA);    // other buffer: no hazard
        sA = nx;                                     // full unroll -> stays in regs
        asm volatile("s_waitcnt lgkmcnt(0)" ::: "memory");
        __builtin_amdgcn_s_barrier();                // vmcnt NOT drained
    }

    // qsq: reduce over the 8 staging threads of each row (lanes ^1^2^4)
    qsq += __shfl_xor(qsq, 1, 64);
    qsq += __shfl_xor(qsq, 2, 64);
    qsq += __shfl_xor(qsq, 4, 64);
    if (sk8 == 0) qsq_s[srow] = qsq;
    __syncthreads();

    float* ob = out + ((size_t)(t * WQ + mt * 64 + wr * 16)) * WAYS;
#pragma unroll
    for (int r = 0; r < 4; ++r) {
        const int row = kg * 4 + r;                  // local row 0..15 in wave's group
        const float qv = qsq_s[wr * 16 + row];
#pragma unroll
        for (int nf = 0; nf < 2; ++nf) {
            ob[(size_t)row * WAYS + wn * 32 + nf * 16 + fr] =
                2.f * acc[nf][r] - qv - psqv[nf];
        }
    }
}

extern "C" void kernel_launch(void* const* d_in, const int* in_sizes, int n_in,
                              void* d_out, int out_size, void* d_ws, size_t ws_size,
                              hipStream_t stream) {
    const float* query   = (const float*)d_in[0];
    const float* support = (const float*)d_in[1];
    float* out = (float*)d_out;

    __bf16* proto = (__bf16*)d_ws;                                   // 4 MB
    float*  p_sq  = (float*)((char*)d_ws + (size_t)T * WAYS * CDIM * sizeof(__bf16));

    hipLaunchKernelGGL(proto_kernel, dim3(T * WAYS), dim3(256), 0, stream,
                       support, proto, p_sq);
    hipLaunchKernelGGL(dist_kernel, dim3(T * 16), dim3(512), 0, stream,
                       query, proto, p_sq, out);
}